// Round 1
// baseline (2727.346 us; speedup 1.0000x reference)
//
#include <hip/hip_runtime.h>
#include <math.h>

// Problem constants (from reference): B,T,E,D,H,C,K
#define NB 64
#define NT 2048
#define NE 512
#define ND 1024
#define NH 128
#define NC 32
#define NK 31
#define NPAD 15
#define TT 16   // t-rows per block in k_erg

// ---------------------------------------------------------------------------
// Kernel 1: wd[b,h] = dec[b,:] @ W[:,h] for both branches; also zero the two
// context output sections of d_out (harness poisons d_out with 0xAA).
// ---------------------------------------------------------------------------
__global__ __launch_bounds__(256) void k_wdec(
    const float* __restrict__ dec, const float* __restrict__ W1,
    const float* __restrict__ W2, float* __restrict__ wd1,
    float* __restrict__ wd2, float* __restrict__ ctxzero)
{
  const int b = blockIdx.x;
  __shared__ float ds[ND];
  for (int i = threadIdx.x; i < ND; i += 256) ds[i] = dec[b * ND + i];
  // zero 2*B*E ctx floats total; this block zeroes its 2*E slice
  for (int i = threadIdx.x; i < 2 * NE; i += 256) ctxzero[b * 2 * NE + i] = 0.f;
  __syncthreads();
  const int h = threadIdx.x & (NH - 1);
  const float* __restrict__ W = (threadIdx.x < NH) ? W1 : W2;
  float acc = 0.f;
#pragma unroll 8
  for (int d = 0; d < ND; ++d) acc += ds[d] * W[d * NH + h];
  if (threadIdx.x < NH) wd1[b * NH + h] = acc;
  else                  wd2[b * NH + h] = acc;
}

// ---------------------------------------------------------------------------
// Kernel 2: fused location-conv + additive-attention energies for BOTH
// branches. One block = (b, 16 t-rows). erg[b,t] = sqrt(erg1*erg2) w/ masks.
// ---------------------------------------------------------------------------
__global__ __launch_bounds__(256, 2) void k_erg(
    const float* __restrict__ eo, const float* __restrict__ po,
    const float* __restrict__ ap,
    const unsigned char* __restrict__ emask, const unsigned char* __restrict__ pmask,
    const float* __restrict__ V1, const float* __restrict__ Vb1,
    const float* __restrict__ U1, const float* __restrict__ F1,
    const float* __restrict__ w1, const float* __restrict__ w1b,
    const float* __restrict__ V2, const float* __restrict__ Vb2,
    const float* __restrict__ U2, const float* __restrict__ F2,
    const float* __restrict__ w2, const float* __restrict__ w2b,
    const float* __restrict__ wd1, const float* __restrict__ wd2,
    float* __restrict__ erg)
{
  const int b = blockIdx.y;
  const int t0 = blockIdx.x * TT;
  const int tid = threadIdx.x;

  // +4 row pad: 4 t-groups per wave land in different banks on xs[t][e] reads
  __shared__ float xs1[TT][NE + 4];   // 33 KB
  __shared__ float xs2[TT][NE + 4];   // 33 KB
  __shared__ float fs[2][TT][NC + 1]; // conv features, padded
  __shared__ float aps[TT + 2 * NPAD];

  // stage x tiles (float4, coalesced)
  const float4* e4 = (const float4*)(eo + ((size_t)b * NT + t0) * NE);
  const float4* p4 = (const float4*)(po + ((size_t)b * NT + t0) * NE);
  for (int i = tid; i < TT * NE / 4; i += 256) {
    const int r = i >> 7;          // / (NE/4)
    const int c4 = i & 127;
    *(float4*)&xs1[r][c4 * 4] = e4[i];
    *(float4*)&xs2[r][c4 * 4] = p4[i];
  }
  // stage att_prev window with zero SAME-padding
  if (tid < TT + 2 * NPAD) {
    const int gt = t0 - NPAD + tid;
    aps[tid] = (gt >= 0 && gt < NT) ? ap[b * NT + gt] : 0.f;
  }
  __syncthreads();

  // location conv: f[br][t][c] = sum_k F[c,k] * ap_window[t+k]
  for (int task = tid; task < 2 * TT * NC; task += 256) {
    const int br = task >> 9;          // / (TT*NC)
    const int rem = task & (TT * NC - 1);
    const int t = rem >> 5, c = rem & (NC - 1);
    const float* __restrict__ F = br ? F2 : F1;
    float s = 0.f;
#pragma unroll
    for (int k = 0; k < NK; ++k) s += F[c * NK + k] * aps[t + k];
    fs[br][t][c] = s;
  }
  __syncthreads();

  // each thread: one t row (t = tid/16), 8 h-columns (h = (tid%16)*8)
  const int t = tid >> 4;
  const int hg = tid & 15;
  const int h = hg * 8;

  float acc1[8], acc2[8];
#pragma unroll
  for (int j = 0; j < 8; ++j) {
    acc1[j] = wd1[b * NH + h + j] + Vb1[h + j];
    acc2[j] = wd2[b * NH + h + j] + Vb2[h + j];
  }
  // + f @ U
#pragma unroll 4
  for (int c = 0; c < NC; ++c) {
    const float f1 = fs[0][t][c], f2 = fs[1][t][c];
    float u1[8], u2[8];
    *(float4*)&u1[0] = *(const float4*)(U1 + c * NH + h);
    *(float4*)&u1[4] = *(const float4*)(U1 + c * NH + h + 4);
    *(float4*)&u2[0] = *(const float4*)(U2 + c * NH + h);
    *(float4*)&u2[4] = *(const float4*)(U2 + c * NH + h + 4);
#pragma unroll
    for (int j = 0; j < 8; ++j) { acc1[j] += f1 * u1[j]; acc2[j] += f2 * u2[j]; }
  }
  // + x @ V (the heavy part): 512 e iterations, 16 fmacs each
#pragma unroll 4
  for (int e = 0; e < NE; ++e) {
    const float x1 = xs1[t][e];
    const float x2 = xs2[t][e];
    float v1r[8], v2r[8];
    *(float4*)&v1r[0] = *(const float4*)(V1 + e * NH + h);
    *(float4*)&v1r[4] = *(const float4*)(V1 + e * NH + h + 4);
    *(float4*)&v2r[0] = *(const float4*)(V2 + e * NH + h);
    *(float4*)&v2r[4] = *(const float4*)(V2 + e * NH + h + 4);
#pragma unroll
    for (int j = 0; j < 8; ++j) { acc1[j] += x1 * v1r[j]; acc2[j] += x2 * v2r[j]; }
  }

  // erg = w . tanh(acc) + wb, reduce over the 16 lanes sharing this t
  float s1 = 0.f, s2 = 0.f;
#pragma unroll
  for (int j = 0; j < 8; ++j) {
    s1 += w1[h + j] * tanhf(acc1[j]);
    s2 += w2[h + j] * tanhf(acc2[j]);
  }
#pragma unroll
  for (int off = 1; off < 16; off <<= 1) {
    s1 += __shfl_xor(s1, off, 16);
    s2 += __shfl_xor(s2, off, 16);
  }
  if (hg == 0) {
    const int gt = t0 + t;
    float e1 = s1 + w1b[0];
    float e2 = s2 + w2b[0];
    if (emask[b * NT + gt]) e1 = -INFINITY;
    if (pmask[b * NT + gt]) e2 = -INFINITY;
    erg[b * NT + gt] = sqrtf(e1 * e2);
  }
}

// ---------------------------------------------------------------------------
// Kernel 3: softmax over T per batch row. One block per b.
// ---------------------------------------------------------------------------
__global__ __launch_bounds__(256) void k_softmax(const float* __restrict__ erg,
                                                 float* __restrict__ attn)
{
  const int b = blockIdx.x, tid = threadIdx.x;
  float v[NT / 256];
  float m = -INFINITY;
#pragma unroll
  for (int i = 0; i < NT / 256; ++i) {
    v[i] = erg[b * NT + i * 256 + tid];
    m = fmaxf(m, v[i]);
  }
#pragma unroll
  for (int off = 32; off > 0; off >>= 1) m = fmaxf(m, __shfl_xor(m, off, 64));
  __shared__ float sm[4];
  if ((tid & 63) == 0) sm[tid >> 6] = m;
  __syncthreads();
  m = fmaxf(fmaxf(sm[0], sm[1]), fmaxf(sm[2], sm[3]));
  float s = 0.f;
#pragma unroll
  for (int i = 0; i < NT / 256; ++i) { v[i] = expf(v[i] - m); s += v[i]; }
#pragma unroll
  for (int off = 32; off > 0; off >>= 1) s += __shfl_xor(s, off, 64);
  __shared__ float ss[4];
  if ((tid & 63) == 0) ss[tid >> 6] = s;
  __syncthreads();
  const float inv = 1.f / (ss[0] + ss[1] + ss[2] + ss[3]);
#pragma unroll
  for (int i = 0; i < NT / 256; ++i) attn[b * NT + i * 256 + tid] = v[i] * inv;
}

// ---------------------------------------------------------------------------
// Kernel 4: ctx[b,e] = sum_t x[b,t,e] * attn[b,t]  (both sources).
// Grid (src*2+echunk, tchunk, b); partial sums atomically added into d_out
// (zeroed by k_wdec). Pure HBM stream: 512 MB.
// ---------------------------------------------------------------------------
__global__ __launch_bounds__(256) void k_ctx(
    const float* __restrict__ eo, const float* __restrict__ po,
    const float* __restrict__ attn, float* __restrict__ out)
{
  const int b = blockIdx.z;
  const int src = blockIdx.x >> 1;
  const int ec = blockIdx.x & 1;
  const int e = ec * 256 + threadIdx.x;
  const int tstart = blockIdx.y * 256;
  const float* __restrict__ x = src ? po : eo;
  const float* __restrict__ a = attn + b * NT + tstart;
  const float* __restrict__ xp = x + ((size_t)b * NT + tstart) * NE + e;
  float acc = 0.f;
#pragma unroll 8
  for (int tt = 0; tt < 256; ++tt) acc += a[tt] * xp[(size_t)tt * NE];
  atomicAdd(&out[src * NB * NE + b * NE + e], acc);
}

// ---------------------------------------------------------------------------
extern "C" void kernel_launch(void* const* d_in, const int* in_sizes, int n_in,
                              void* d_out, int out_size, void* d_ws, size_t ws_size,
                              hipStream_t stream)
{
  const float* eo  = (const float*)d_in[0];
  const float* po  = (const float*)d_in[2];
  const float* dec = (const float*)d_in[4];
  const float* ap  = (const float*)d_in[5];
  const unsigned char* emask = (const unsigned char*)d_in[6];
  const unsigned char* pmask = (const unsigned char*)d_in[7];
  const float* V1  = (const float*)d_in[8];
  const float* Vb1 = (const float*)d_in[9];
  const float* W1  = (const float*)d_in[10];
  const float* U1  = (const float*)d_in[11];
  const float* F1  = (const float*)d_in[12];
  const float* w1  = (const float*)d_in[13];
  const float* w1b = (const float*)d_in[14];
  const float* V2  = (const float*)d_in[15];
  const float* Vb2 = (const float*)d_in[16];
  const float* W2  = (const float*)d_in[17];
  const float* U2  = (const float*)d_in[18];
  const float* F2  = (const float*)d_in[19];
  const float* w2  = (const float*)d_in[20];
  const float* w2b = (const float*)d_in[21];

  float* out = (float*)d_out;
  float* ws = (float*)d_ws;
  float* wd1 = ws;                       // B*H
  float* wd2 = ws + NB * NH;             // B*H
  float* erg = ws + 2 * NB * NH;         // B*T
  float* attn = out + 2 * NB * NE;       // third output section

  k_wdec<<<dim3(NB), 256, 0, stream>>>(dec, W1, W2, wd1, wd2, out);
  k_erg<<<dim3(NT / TT, NB), 256, 0, stream>>>(
      eo, po, ap, emask, pmask,
      V1, Vb1, U1, F1, w1, w1b,
      V2, Vb2, U2, F2, w2, w2b,
      wd1, wd2, erg);
  k_softmax<<<dim3(NB), 256, 0, stream>>>(erg, attn);
  k_ctx<<<dim3(4, 8, NB), 256, 0, stream>>>(eo, po, attn, out);
}

// Round 2
// 865.068 us; speedup vs baseline: 3.1528x; 3.1528x over previous
//
#include <hip/hip_runtime.h>
#include <math.h>

#define NB 64
#define NT 2048
#define NE 512
#define ND 1024
#define NH 128
#define NC 32
#define NK 31
#define NPAD 15

#define TTILE 256      // t-rows per block in k_erg
#define EC 32          // K-chunk width
#define NCH 17         // 16 X-chunks + 1 conv-feature chunk
#define ECOLS 544      // Vt columns: 512 V^T + 32 U^T

typedef __attribute__((ext_vector_type(8))) short short8;
typedef __attribute__((ext_vector_type(4))) float floatx4;

__device__ __forceinline__ unsigned short f2bf(float f) {
  union { float f; unsigned u; } v; v.f = f;
  unsigned r = v.u + 0x7fffu + ((v.u >> 16) & 1u);
  return (unsigned short)(r >> 16);
}

// ---------------------------------------------------------------------------
// k_prep: blocks 0..255 build Vt[br][h][544] bf16 (V^T | U^T);
//         blocks 256..319 compute wdv[br][b][h] = dec@W + Vb and zero ctx out.
// ---------------------------------------------------------------------------
__global__ __launch_bounds__(256) void k_prep(
    const float* __restrict__ V1, const float* __restrict__ U1,
    const float* __restrict__ V2, const float* __restrict__ U2,
    const float* __restrict__ dec, const float* __restrict__ W1,
    const float* __restrict__ W2, const float* __restrict__ Vb1,
    const float* __restrict__ Vb2,
    unsigned short* __restrict__ Vt, float* __restrict__ wdv,
    float* __restrict__ ctxzero)
{
  const int bid = blockIdx.x;
  if (bid < 256) {
    const int br = bid >> 7, h = bid & 127;
    const float* __restrict__ V = br ? V2 : V1;
    const float* __restrict__ U = br ? U2 : U1;
    unsigned short* __restrict__ dst = Vt + (size_t)(br * NH + h) * ECOLS;
    for (int e = threadIdx.x; e < ECOLS; e += 256) {
      float v = (e < NE) ? V[e * NH + h] : U[(e - NE) * NH + h];
      dst[e] = f2bf(v);
    }
  } else {
    const int b = bid - 256;
    __shared__ float ds[ND];
    for (int i = threadIdx.x; i < ND; i += 256) ds[i] = dec[b * ND + i];
    for (int i = threadIdx.x; i < 2 * NE; i += 256) ctxzero[b * 2 * NE + i] = 0.f;
    __syncthreads();
    const int h = threadIdx.x & (NH - 1);
    const int br = threadIdx.x >> 7;
    const float* __restrict__ W = br ? W2 : W1;
    float acc = (br ? Vb2 : Vb1)[h];
#pragma unroll 8
    for (int d = 0; d < ND; ++d) acc += ds[d] * W[d * NH + h];
    wdv[(br * NB + b) * NH + h] = acc;
  }
}

// ---------------------------------------------------------------------------
// k_erg: bf16 MFMA fused energies.
// LDS layout (bytes), all tiles XOR-swizzled with ((row&7)<<4):
//   XS(buf,br) = (buf*2+br)*16384        [256 t][32 bf16 = 64B]   (x tiles)
//   VS(buf,br) = 65536 + (buf*2+br)*8192 [128 h][32 bf16 = 64B]   (Vt chunk)
//   FS(br)     = 98304 + br*16384        [256 t][32 bf16]         (conv feats)
//   ERGS       = 131072  float[2][256]
//   APS        = 133120  float[288]
// ---------------------------------------------------------------------------
#define LDS_XS(buf, br) (((buf) * 2 + (br)) * 16384)
#define LDS_VS(buf, br) (65536 + ((buf) * 2 + (br)) * 8192)
#define LDS_FS(br)      (98304 + (br) * 16384)
#define LDS_ERGS        131072
#define LDS_APS         133120
#define LDS_BYTES       134400

__global__ __launch_bounds__(512, 2) void k_erg(
    const float* __restrict__ eo, const float* __restrict__ po,
    const float* __restrict__ ap,
    const unsigned char* __restrict__ emask, const unsigned char* __restrict__ pmask,
    const unsigned short* __restrict__ Vt, const float* __restrict__ wdv,
    const float* __restrict__ F1, const float* __restrict__ F2,
    const float* __restrict__ w1, const float* __restrict__ w1b,
    const float* __restrict__ w2, const float* __restrict__ w2b,
    float* __restrict__ erg)
{
  __shared__ __align__(16) char lds[LDS_BYTES];
  const int b = blockIdx.y;
  const int t0 = blockIdx.x * TTILE;
  const int tid = threadIdx.x;
  const int wid = tid >> 6, lane = tid & 63;
  const int br = wid >> 2, tq = wid & 3;   // branch, t-quarter (64 rows)
  const int lr = lane & 15, lg = lane >> 4;

  const float* __restrict__ Xg0 = eo + ((size_t)b * NT + t0) * NE;
  const float* __restrict__ Xg1 = po + ((size_t)b * NT + t0) * NE;

  // staging unit assignment (per thread, fixed)
  int xu_br[4], xu_r[4], xu_c[4];   // 4 pairs of float4 (8 floats each)
#pragma unroll
  for (int i = 0; i < 4; ++i) {
    const int u2 = i * 512 + tid;
    xu_br[i] = u2 >> 10; const int rem = u2 & 1023;
    xu_r[i] = rem >> 2; xu_c[i] = (rem & 3) * 8;       // float col
  }
  int vu_br[2], vu_h[2], vu_c[2];   // 2 uint4 (8 bf16 each)
#pragma unroll
  for (int i = 0; i < 2; ++i) {
    const int vu = i * 512 + tid;
    vu_br[i] = vu >> 9; const int rem = vu & 511;
    vu_h[i] = rem >> 2; vu_c[i] = (rem & 3) * 8;       // short col
  }

  float4 xreg[4][2];
  uint4  vreg[2];

#define STAGE_LOAD(ch) do {                                                   \
    const int e0_ = (ch) * EC;                                                \
    if ((ch) < 16) {                                                          \
      _Pragma("unroll")                                                       \
      for (int i = 0; i < 4; ++i) {                                           \
        const float* p_ = (xu_br[i] ? Xg1 : Xg0) +                            \
                          (size_t)xu_r[i] * NE + e0_ + xu_c[i];               \
        xreg[i][0] = *(const float4*)p_;                                      \
        xreg[i][1] = *(const float4*)(p_ + 4);                                \
      }                                                                       \
    }                                                                         \
    _Pragma("unroll")                                                         \
    for (int i = 0; i < 2; ++i)                                               \
      vreg[i] = *(const uint4*)(Vt + (size_t)(vu_br[i] * NH + vu_h[i]) * ECOLS\
                                + e0_ + vu_c[i]);                             \
  } while (0)

#define STAGE_WRITE(ch, buf) do {                                             \
    if ((ch) < 16) {                                                          \
      _Pragma("unroll")                                                       \
      for (int i = 0; i < 4; ++i) {                                           \
        const float4 A_ = xreg[i][0], B_ = xreg[i][1];                        \
        short8 s_ = (short8){(short)f2bf(A_.x), (short)f2bf(A_.y),            \
                             (short)f2bf(A_.z), (short)f2bf(A_.w),            \
                             (short)f2bf(B_.x), (short)f2bf(B_.y),            \
                             (short)f2bf(B_.z), (short)f2bf(B_.w)};           \
        const int off_ = LDS_XS(buf, xu_br[i]) +                              \
            ((xu_r[i] * 64 + xu_c[i] * 2) ^ ((xu_r[i] & 7) << 4));            \
        *(short8*)(lds + off_) = s_;                                          \
      }                                                                       \
    }                                                                         \
    _Pragma("unroll")                                                         \
    for (int i = 0; i < 2; ++i) {                                             \
      const int off_ = LDS_VS(buf, vu_br[i]) +                                \
          ((vu_h[i] * 64 + vu_c[i] * 2) ^ ((vu_h[i] & 7) << 4));              \
      *(uint4*)(lds + off_) = vreg[i];                                        \
    }                                                                         \
  } while (0)

  // MFMA fragment LDS offsets (swizzled, loop-invariant)
  int aoff[4], boff[8];
#pragma unroll
  for (int s = 0; s < 4; ++s) {
    const int t = tq * 64 + s * 16 + lr;
    aoff[s] = (t * 64 + lg * 16) ^ ((t & 7) << 4);
  }
#pragma unroll
  for (int j = 0; j < 8; ++j) {
    const int h = j * 16 + lr;
    boff[j] = (h * 64 + lg * 16) ^ ((h & 7) << 4);
  }

  // ---- prologue: chunk-0 loads in flight, conv features, acc init
  STAGE_LOAD(0);

  float* aps = (float*)(lds + LDS_APS);
  for (int i = tid; i < TTILE + 2 * NPAD; i += 512) {
    const int gt = t0 - NPAD + i;
    aps[i] = (gt >= 0 && gt < NT) ? ap[b * NT + gt] : 0.f;
  }
  // conv coefficient prefetch: thread -> (cbr, cc, tg)
  const int cbr = tid >> 8, crem = tid & 255, cc = crem >> 3, tg = crem & 7;
  const float* __restrict__ Fp = cbr ? F2 : F1;
  float fco[NK];
#pragma unroll
  for (int k = 0; k < NK; ++k) fco[k] = Fp[cc * NK + k];

  // accumulator init from wdv (f32-exact bias path) + hoist w
  float wreg[8];
  floatx4 acc[4][8];
  {
    const float* __restrict__ wsel = br ? w2 : w1;
#pragma unroll
    for (int j = 0; j < 8; ++j) {
      const int h = j * 16 + lr;
      const float wi = wdv[(br * NB + b) * NH + h];
      wreg[j] = wsel[h];
#pragma unroll
      for (int s = 0; s < 4; ++s) acc[s][j] = (floatx4){wi, wi, wi, wi};
    }
  }

  __syncthreads();   // aps visible

  // conv -> FS (bf16, swizzled): 32 t-rows per thread, one c
#pragma unroll 4
  for (int t = 0; t < 32; ++t) {
    const int tloc = tg * 32 + t;
    float s = 0.f;
#pragma unroll
    for (int k = 0; k < NK; ++k) s += fco[k] * aps[tloc + k];
    *(unsigned short*)(lds + LDS_FS(cbr) +
        ((tloc * 64 + cc * 2) ^ ((tloc & 7) << 4))) = f2bf(s);
  }

  STAGE_WRITE(0, 0);
  __syncthreads();

  // ---- main loop: 17 K-chunks, double-buffered
#pragma unroll 1
  for (int c = 0; c < NCH; ++c) {
    if (c + 1 < NCH) STAGE_LOAD(c + 1);

    {
      const char* __restrict__ ab =
          lds + ((c == 16) ? LDS_FS(br) : LDS_XS(c & 1, br));
      const char* __restrict__ vb = lds + LDS_VS(c & 1, br);
      short8 bfr[8];
#pragma unroll
      for (int j = 0; j < 8; ++j) bfr[j] = *(const short8*)(vb + boff[j]);
#pragma unroll
      for (int s = 0; s < 4; ++s) {
        const short8 af = *(const short8*)(ab + aoff[s]);
#pragma unroll
        for (int j = 0; j < 8; ++j)
          acc[s][j] = __builtin_amdgcn_mfma_f32_16x16x32_bf16(
              af, bfr[j], acc[s][j], 0, 0, 0);
      }
    }

    __syncthreads();
    if (c + 1 < NCH) STAGE_WRITE(c + 1, (c + 1) & 1);
    __syncthreads();
  }

  // ---- epilogue: erg_partial[t] = sum_h w[h]*tanh(acc), 16-lane reduce
  float* ergs = (float*)(lds + LDS_ERGS);
#pragma unroll
  for (int s = 0; s < 4; ++s) {
#pragma unroll
    for (int r = 0; r < 4; ++r) {
      float p = 0.f;
#pragma unroll
      for (int j = 0; j < 8; ++j) p += wreg[j] * tanhf(acc[s][j][r]);
      p += __shfl_xor(p, 1);
      p += __shfl_xor(p, 2);
      p += __shfl_xor(p, 4);
      p += __shfl_xor(p, 8);
      if (lr == 0) ergs[br * 256 + tq * 64 + s * 16 + lg * 4 + r] = p;
    }
  }
  __syncthreads();
  if (tid < 256) {
    const int gt = t0 + tid;
    float e1 = ergs[tid] + w1b[0];
    float e2 = ergs[256 + tid] + w2b[0];
    if (emask[b * NT + gt]) e1 = -INFINITY;
    if (pmask[b * NT + gt]) e2 = -INFINITY;
    erg[b * NT + gt] = sqrtf(e1 * e2);
  }
}

// ---------------------------------------------------------------------------
// k_softmax: one block per batch row, in-place safe.
// ---------------------------------------------------------------------------
__global__ __launch_bounds__(256) void k_softmax(const float* __restrict__ erg,
                                                 float* __restrict__ attn)
{
  const int b = blockIdx.x, tid = threadIdx.x;
  float v[NT / 256];
  float m = -INFINITY;
#pragma unroll
  for (int i = 0; i < NT / 256; ++i) {
    v[i] = erg[b * NT + i * 256 + tid];
    m = fmaxf(m, v[i]);
  }
#pragma unroll
  for (int off = 32; off > 0; off >>= 1) m = fmaxf(m, __shfl_xor(m, off, 64));
  __shared__ float sm[4];
  if ((tid & 63) == 0) sm[tid >> 6] = m;
  __syncthreads();
  m = fmaxf(fmaxf(sm[0], sm[1]), fmaxf(sm[2], sm[3]));
  float s = 0.f;
#pragma unroll
  for (int i = 0; i < NT / 256; ++i) { v[i] = expf(v[i] - m); s += v[i]; }
#pragma unroll
  for (int off = 32; off > 0; off >>= 1) s += __shfl_xor(s, off, 64);
  __shared__ float ss[4];
  if ((tid & 63) == 0) ss[tid >> 6] = s;
  __syncthreads();
  const float inv = 1.f / (ss[0] + ss[1] + ss[2] + ss[3]);
#pragma unroll
  for (int i = 0; i < NT / 256; ++i) attn[b * NT + i * 256 + tid] = v[i] * inv;
}

// ---------------------------------------------------------------------------
// k_ctx: ctx[b,e] = sum_t x[b,t,e]*attn[b,t], float4 coalesced.
// grid (src*16 + tchunk, b); atomics into prep-zeroed out.
// ---------------------------------------------------------------------------
__global__ __launch_bounds__(256) void k_ctx(
    const float* __restrict__ eo, const float* __restrict__ po,
    const float* __restrict__ attn, float* __restrict__ out)
{
  const int b = blockIdx.y;
  const int src = blockIdx.x >> 4;
  const int tc = blockIdx.x & 15;
  const int e4 = threadIdx.x & 127;
  const int th = threadIdx.x >> 7;
  const int t0 = tc * 128 + th * 64;
  const float* __restrict__ X = src ? po : eo;
  const float4* __restrict__ xp =
      (const float4*)(X + ((size_t)b * NT + t0) * NE) + e4;
  const float* __restrict__ a = attn + b * NT + t0;
  float4 acc = {0.f, 0.f, 0.f, 0.f};
#pragma unroll 8
  for (int tt = 0; tt < 64; ++tt) {
    const float av = a[tt];
    const float4 x = xp[(size_t)tt * 128];
    acc.x += av * x.x; acc.y += av * x.y;
    acc.z += av * x.z; acc.w += av * x.w;
  }
  float* o = out + src * NB * NE + b * NE + e4 * 4;
  atomicAdd(o + 0, acc.x); atomicAdd(o + 1, acc.y);
  atomicAdd(o + 2, acc.z); atomicAdd(o + 3, acc.w);
}

// ---------------------------------------------------------------------------
extern "C" void kernel_launch(void* const* d_in, const int* in_sizes, int n_in,
                              void* d_out, int out_size, void* d_ws, size_t ws_size,
                              hipStream_t stream)
{
  const float* eo  = (const float*)d_in[0];
  const float* po  = (const float*)d_in[2];
  const float* dec = (const float*)d_in[4];
  const float* ap  = (const float*)d_in[5];
  const unsigned char* emask = (const unsigned char*)d_in[6];
  const unsigned char* pmask = (const unsigned char*)d_in[7];
  const float* V1  = (const float*)d_in[8];
  const float* Vb1 = (const float*)d_in[9];
  const float* W1  = (const float*)d_in[10];
  const float* U1  = (const float*)d_in[11];
  const float* F1  = (const float*)d_in[12];
  const float* w1  = (const float*)d_in[13];
  const float* w1b = (const float*)d_in[14];
  const float* V2  = (const float*)d_in[15];
  const float* Vb2 = (const float*)d_in[16];
  const float* W2  = (const float*)d_in[17];
  const float* U2  = (const float*)d_in[18];
  const float* F2  = (const float*)d_in[19];
  const float* w2  = (const float*)d_in[20];
  const float* w2b = (const float*)d_in[21];

  float* out = (float*)d_out;
  unsigned short* Vt = (unsigned short*)d_ws;                 // 2*128*544*2 = 278528 B
  float* wdv = (float*)((char*)d_ws + 278528);                // 2*64*128*4  = 65536 B
  float* attn = out + 2 * NB * NE;  // erg lives here, softmax'd in place

  k_prep<<<dim3(320), 256, 0, stream>>>(V1, U1, V2, U2, dec, W1, W2, Vb1, Vb2,
                                        Vt, wdv, out);
  k_erg<<<dim3(NT / TTILE, NB), 512, 0, stream>>>(
      eo, po, ap, emask, pmask, Vt, wdv, F1, F2, w1, w1b, w2, w2b, attn);
  k_softmax<<<dim3(NB), 256, 0, stream>>>(attn, attn);
  k_ctx<<<dim3(32, NB), 256, 0, stream>>>(eo, po, attn, out);
}